// Round 3
// baseline (2694.634 us; speedup 1.0000x reference)
//
#include <hip/hip_runtime.h>
#include <hip/hip_bf16.h>

#define KD 4096
#define ND 11008
#define MD 16384
#define KGD 32

typedef __hip_bfloat16 bf16;
typedef float f32x4 __attribute__((ext_vector_type(4)));
typedef short bf16x8 __attribute__((ext_vector_type(8)));

// ---------------------------------------------------------------------------
// Phase 1: dequant packed int4 -> bf16, W_deq[(local)row][k], row-major (N,K).
// scales are fp32 on device (reference fp16 -> harness fp32).
// ---------------------------------------------------------------------------
__global__ void dequant_kernel(const int* __restrict__ wp, const float* __restrict__ sc,
                               bf16* __restrict__ wd, int n0, int rows) {
    const int per_row = KD / 8;  // 512 int32-quads per row
    int t = blockIdx.x * blockDim.x + threadIdx.x;
    if (t >= rows * per_row) return;
    int lr = t / per_row;        // local row within chunk
    int q  = t - lr * per_row;
    int n  = n0 + lr;
    int j  = q * 4;              // packed index; covers k in [2j, 2j+8)
    const int4 p = *reinterpret_cast<const int4*>(wp + (size_t)n * (KD / 2) + j);
    float s = sc[(size_t)n * KGD + (j >> 6)];  // kg = 2j/128 = j/64
    int v[4] = {p.x, p.y, p.z, p.w};
    bf16 o[8];
#pragma unroll
    for (int i = 0; i < 4; ++i) {
        o[2 * i]     = __float2bfloat16((float)((v[i] & 0xF) - 8) * s);        // even k
        o[2 * i + 1] = __float2bfloat16((float)(((v[i] >> 4) & 0xF) - 8) * s); // odd k
    }
    *reinterpret_cast<bf16x8*>(wd + (size_t)lr * KD + j * 2) = *reinterpret_cast<bf16x8*>(o);
}

// ---------------------------------------------------------------------------
// Phase 2: C[M,N] = A[M,K] * B[N,K]^T.  A fp32 in global (cvt->bf16 at
// staging), B bf16 (dequant ws), C fp32 out. fp32 MFMA accum.
// 128x128 tile, BK=64, 256 threads = 4 waves (2x2), 4x4 16x16x32 frags/wave.
// Register-staged LDS (global->VGPR->cvt->ds_write_b128), linear LDS layout.
// ---------------------------------------------------------------------------
__global__ __launch_bounds__(256) void gemm128(const float* __restrict__ A,
                                               const bf16* __restrict__ B,
                                               float* __restrict__ C,
                                               int n0) {
    __shared__ bf16 sA[128 * 64];
    __shared__ bf16 sB[128 * 64];
    const int tid  = threadIdx.x;
    const int lane = tid & 63;
    const int wave = tid >> 6;
    const int m0 = blockIdx.x * 128;
    const int bn = blockIdx.y * 128;  // row offset within dequant chunk
    const int wm = wave >> 1, wn = wave & 1;
    const int lrow = lane & 15;       // fragment row/col within 16
    const int kq   = lane >> 4;       // k-block (x8 elems)

    // staging geometry: wave covers 32 rows; each round = 8 rows x 64 k (1 KiB bf16)
    const int srow = wave * 32;
    const int lr = lane >> 3;         // 0..7 : row within round
    const int lk = (lane & 7) * 8;    // element offset within row (8 elems/lane)

    const float* Abase = A + (size_t)(m0 + srow) * KD;
    const bf16*  Bbase = B + (size_t)(bn + srow) * KD;

    f32x4 acc[4][4] = {};

    for (int k0 = 0; k0 < KD; k0 += 64) {
        // issue global loads early: HBM latency overlaps previous iter's MFMA
        f32x4 va[4][2];
        bf16x8 vb[4];
#pragma unroll
        for (int i = 0; i < 4; ++i) {
            const float* ap = Abase + (size_t)(i * 8 + lr) * KD + k0 + lk;
            va[i][0] = *reinterpret_cast<const f32x4*>(ap);
            va[i][1] = *reinterpret_cast<const f32x4*>(ap + 4);
            vb[i] = *reinterpret_cast<const bf16x8*>(Bbase + (size_t)(i * 8 + lr) * KD + k0 + lk);
        }
        __syncthreads();  // all waves done reading LDS from previous iter
#pragma unroll
        for (int i = 0; i < 4; ++i) {
            bf16 ta[8];
#pragma unroll
            for (int e = 0; e < 4; ++e) {
                ta[e]     = __float2bfloat16(va[i][0][e]);
                ta[4 + e] = __float2bfloat16(va[i][1][e]);
            }
            // linear blob: row (srow+i*8+lr), k offset lk  ==  base + lane*8
            *reinterpret_cast<bf16x8*>(&sA[(srow + i * 8) * 64 + lane * 8]) =
                *reinterpret_cast<bf16x8*>(ta);
            *reinterpret_cast<bf16x8*>(&sB[(srow + i * 8) * 64 + lane * 8]) = vb[i];
        }
        __syncthreads();  // tiles visible to all waves
#pragma unroll
        for (int kk = 0; kk < 64; kk += 32) {
            bf16x8 af[4], bfr[4];
#pragma unroll
            for (int mi = 0; mi < 4; ++mi)
                af[mi] = *reinterpret_cast<const bf16x8*>(
                    &sA[(wm * 64 + mi * 16 + lrow) * 64 + kk + kq * 8]);
#pragma unroll
            for (int ni = 0; ni < 4; ++ni)
                bfr[ni] = *reinterpret_cast<const bf16x8*>(
                    &sB[(wn * 64 + ni * 16 + lrow) * 64 + kk + kq * 8]);
#pragma unroll
            for (int mi = 0; mi < 4; ++mi)
#pragma unroll
                for (int ni = 0; ni < 4; ++ni)
                    acc[mi][ni] = __builtin_amdgcn_mfma_f32_16x16x32_bf16(
                        af[mi], bfr[ni], acc[mi][ni], 0, 0, 0);
        }
    }

    // epilogue: C/D layout col=lane&15, row=(lane>>4)*4+r ; fp32 out
    const int crow0 = m0 + wm * 64;
    const int ccol0 = n0 + bn + wn * 64;
#pragma unroll
    for (int mi = 0; mi < 4; ++mi) {
#pragma unroll
        for (int r = 0; r < 4; ++r) {
            int row = crow0 + mi * 16 + kq * 4 + r;
            float* crow = C + (size_t)row * ND + ccol0;
#pragma unroll
            for (int ni = 0; ni < 4; ++ni)
                crow[ni * 16 + lrow] = acc[mi][ni][r];
        }
    }
}

extern "C" void kernel_launch(void* const* d_in, const int* in_sizes, int n_in,
                              void* d_out, int out_size, void* d_ws, size_t ws_size,
                              hipStream_t stream) {
    const float* x  = (const float*)d_in[0];   // fp16 in reference -> fp32 on device
    const int*   wp = (const int*)d_in[1];
    const float* sc = (const float*)d_in[2];   // fp16 in reference -> fp32 on device
    float* out = (float*)d_out;                // fp16 in reference -> fp32 on device

    // chunk W rows so the dequantized chunk fits in d_ws (rows multiple of 128;
    // N = 86*128 so every chunk stays 128-aligned)
    const size_t row_bytes = (size_t)KD * sizeof(bf16);
    int max_rows = (int)(ws_size / row_bytes);
    int nc = (max_rows / 128) * 128;
    if (nc <= 0) return;  // ws too small (not expected: needs >= 1 MiB)
    if (nc > ND) nc = ND;

    for (int n0 = 0; n0 < ND; n0 += nc) {
        int rows = (ND - n0 < nc) ? (ND - n0) : nc;
        int total_threads = rows * (KD / 8);
        dequant_kernel<<<(total_threads + 255) / 256, 256, 0, stream>>>(
            wp, sc, (bf16*)d_ws, n0, rows);
        dim3 grid(MD / 128, rows / 128);
        gemm128<<<grid, 256, 0, stream>>>(x, (const bf16*)d_ws, out, n0);
    }
}

// Round 4
// 1462.589 us; speedup vs baseline: 1.8424x; 1.8424x over previous
//
#include <hip/hip_runtime.h>
#include <hip/hip_bf16.h>

#define KD 4096
#define ND 11008
#define MD 16384
#define KGD 32
#define NT (KD / 64)

typedef __hip_bfloat16 bf16;
typedef float f32x4 __attribute__((ext_vector_type(4)));
typedef short bf16x8 __attribute__((ext_vector_type(8)));

#define WAITV(n) asm volatile("s_waitcnt vmcnt(" #n ")" ::: "memory")

__device__ __forceinline__ void gload16(const bf16* g, bf16* l) {
    __builtin_amdgcn_global_load_lds((const __attribute__((address_space(1))) void*)g,
                                     (__attribute__((address_space(3))) void*)l, 16, 0, 0);
}

// ---------------------------------------------------------------------------
// x: fp32 -> bf16 (8 elems/thread)
// ---------------------------------------------------------------------------
__global__ void cvt_kernel(const float* __restrict__ x, bf16* __restrict__ y, int n8) {
    int i = blockIdx.x * blockDim.x + threadIdx.x;
    if (i >= n8) return;
    const f32x4* p = reinterpret_cast<const f32x4*>(x + (size_t)i * 8);
    f32x4 a = p[0], b = p[1];
    bf16 o[8];
#pragma unroll
    for (int e = 0; e < 4; ++e) {
        o[e]     = __float2bfloat16(a[e]);
        o[4 + e] = __float2bfloat16(b[e]);
    }
    *reinterpret_cast<bf16x8*>(y + (size_t)i * 8) = *reinterpret_cast<bf16x8*>(o);
}

// ---------------------------------------------------------------------------
// dequant packed int4 -> bf16 rows [n0 .. n0+rows) into wd (chunk-local)
// ---------------------------------------------------------------------------
__global__ void dequant_kernel(const int* __restrict__ wp, const float* __restrict__ sc,
                               bf16* __restrict__ wd, int n0, int rows) {
    const int per_row = KD / 8;
    int t = blockIdx.x * blockDim.x + threadIdx.x;
    if (t >= rows * per_row) return;
    int lr = t / per_row;
    int q  = t - lr * per_row;
    int n  = n0 + lr;
    int j  = q * 4;
    const int4 p = *reinterpret_cast<const int4*>(wp + (size_t)n * (KD / 2) + j);
    float s = sc[(size_t)n * KGD + (j >> 6)];
    int v[4] = {p.x, p.y, p.z, p.w};
    bf16 o[8];
#pragma unroll
    for (int i = 0; i < 4; ++i) {
        o[2 * i]     = __float2bfloat16((float)((v[i] & 0xF) - 8) * s);
        o[2 * i + 1] = __float2bfloat16((float)(((v[i] >> 4) & 0xF) - 8) * s);
    }
    *reinterpret_cast<bf16x8*>(wd + (size_t)lr * KD + j * 2) = *reinterpret_cast<bf16x8*>(o);
}

// ---------------------------------------------------------------------------
// GEMM: C[M,N] = A[M,K] * B[N,K]^T, all bf16 in, fp32 out.
// 256x256 tile, BK=64 split into two K=32 units per operand, 512 thr / 8 waves
// (2M x 4N), per-wave out 128x64. Double-buffered 128 KiB LDS, global_load_lds
// staging with pre-swizzled source (chunk sigma = c ^ ((r>>1)&3), conflict-free
// ds_read_b128), counted vmcnt(8) pipeline (never 0 in main loop), raw
// s_barrier, setprio around MFMA clusters.
// ---------------------------------------------------------------------------
__global__ __launch_bounds__(512, 2) void gemm256(const bf16* __restrict__ A,
                                                  const bf16* __restrict__ B,
                                                  float* __restrict__ C,
                                                  int mtiles, int ntiles, int n0base) {
    __shared__ bf16 lds[2][2][2][8192];  // [buf][kh][op(A/B)][256 rows x 32 k, swizzled]
    const int tid  = threadIdx.x;
    const int lane = tid & 63;
    const int w    = tid >> 6;

    // bijective XCD-aware block swizzle (n fastest: consecutive share A-panel)
    int nwg = mtiles * ntiles;
    int orig = blockIdx.x;
    int q8 = nwg >> 3, r8 = nwg & 7;
    int xcd = orig & 7, off = orig >> 3;
    int wg = (xcd < r8 ? xcd * (q8 + 1) : r8 * (q8 + 1) + (xcd - r8) * q8) + off;
    const int mb = wg / ntiles, nb = wg - mb * ntiles;
    const int m0 = mb * 256, n0 = nb * 256;

    const int wm = w >> 2, wn = w & 3;
    const int rl = lane & 15, kq = lane >> 4;
    const int sz = (rl >> 1) & 3;
    const int ro = 8 * (kq ^ sz);          // swizzled k-chunk for ds_read

    // staging source (per-lane pre-swizzle so linear LDS dest == swizzled layout)
    const int src_c = (((lane & 3) ^ ((lane >> 3) & 3)) << 3);  // elem offset in k
    const int src_r = (w << 4) + (lane >> 2);                   // row (+128 for issue 1)
    const bf16* Abase = A + (size_t)(m0 + src_r) * KD + src_c;
    const bf16* Bbase = B + (size_t)(n0 + src_r) * KD + src_c;

    f32x4 acc[8][4] = {};

    auto stage = [&](int buf, int kh, int k0) {
        const bf16* ga = Abase + k0 + kh * 32;
        const bf16* gb = Bbase + k0 + kh * 32;
        bf16* la = &lds[buf][kh][0][w * 512];
        bf16* lb = &lds[buf][kh][1][w * 512];
        gload16(ga, la);
        gload16(ga + (size_t)128 * KD, la + 4096);
        gload16(gb, lb);
        gload16(gb + (size_t)128 * KD, lb + 4096);
    };

    auto compute = [&](int buf, int kh) {
        const bf16* ua = &lds[buf][kh][0][0];
        const bf16* ub = &lds[buf][kh][1][0];
        bf16x8 af[8], bfr[4];
#pragma unroll
        for (int mi = 0; mi < 8; ++mi)
            af[mi] = *reinterpret_cast<const bf16x8*>(&ua[(wm * 128 + mi * 16 + rl) * 32 + ro]);
#pragma unroll
        for (int ni = 0; ni < 4; ++ni)
            bfr[ni] = *reinterpret_cast<const bf16x8*>(&ub[(wn * 64 + ni * 16 + rl) * 32 + ro]);
        __builtin_amdgcn_s_setprio(1);
#pragma unroll
        for (int mi = 0; mi < 8; ++mi)
#pragma unroll
            for (int ni = 0; ni < 4; ++ni)
                acc[mi][ni] = __builtin_amdgcn_mfma_f32_16x16x32_bf16(
                    af[mi], bfr[ni], acc[mi][ni], 0, 0, 0);
        __builtin_amdgcn_s_setprio(0);
    };

    // prologue: tile 0, both K-halves -> buf 0 (queue: [Ak0,Ak0,Bk0,Bk0,Ak1,Ak1,Bk1,Bk1])
    stage(0, 0, 0);
    stage(0, 1, 0);

    for (int t = 0; t < NT - 1; ++t) {
        const int cur = t & 1, nxt = cur ^ 1, k0n = (t + 1) * 64;
        stage(nxt, 0, k0n);     // +4 -> 12 outstanding
        WAITV(8);               // tile t's kh0 pair landed
        __builtin_amdgcn_s_barrier();
        compute(cur, 0);
        stage(nxt, 1, k0n);     // +4 -> <=12
        WAITV(8);               // tile t's kh1 pair landed (newest 8 = tile t+1)
        __builtin_amdgcn_s_barrier();
        compute(cur, 1);
    }
    // tail: tile NT-1 sits in buf 1 (NT-1 = 63 odd); drain 4 -> 0
    WAITV(4);
    __builtin_amdgcn_s_barrier();
    compute(1, 0);
    WAITV(0);
    __builtin_amdgcn_s_barrier();
    compute(1, 1);

    // epilogue: C/D layout col=lane&15, row=(lane>>4)*4+r ; fp32 out
    const int crow = m0 + wm * 128 + kq * 4;
    const int ccol = n0base + n0 + wn * 64 + rl;
#pragma unroll
    for (int mi = 0; mi < 8; ++mi) {
#pragma unroll
        for (int r = 0; r < 4; ++r) {
            float* cp = C + (size_t)(crow + mi * 16 + r) * ND + ccol;
#pragma unroll
            for (int ni = 0; ni < 4; ++ni)
                cp[ni * 16] = acc[mi][ni][r];
        }
    }
}

extern "C" void kernel_launch(void* const* d_in, const int* in_sizes, int n_in,
                              void* d_out, int out_size, void* d_ws, size_t ws_size,
                              hipStream_t stream) {
    const float* x  = (const float*)d_in[0];
    const int*   wp = (const int*)d_in[1];
    const float* sc = (const float*)d_in[2];
    float* out = (float*)d_out;

    // partition ws into x-bf16 chunk (mc rows) + W-bf16 chunk (nc rows), both x256
    long long rows_cap = (long long)(ws_size / ((size_t)KD * 2));
    int mc, nc;
    if (rows_cap >= MD + 256) {
        mc = MD;
        long long r = rows_cap - MD;
        nc = (int)((r / 256) * 256);
        if (nc > ND) nc = ND;
    } else if (rows_cap >= ND + 256) {
        nc = ND;
        long long r = rows_cap - ND;
        mc = (int)((r / 256) * 256);
        if (mc > MD) mc = MD;
    } else {
        nc = (int)(((rows_cap / 2) / 256) * 256);
        if (nc > ND) nc = ND;
        long long r = rows_cap - nc;
        mc = (int)((r / 256) * 256);
        if (mc > MD) mc = MD;
        if (mc <= 0 || nc <= 0) return;
    }

    bf16* xbuf = (bf16*)d_ws;
    bf16* wbuf = xbuf + (size_t)mc * KD;

    for (int m0 = 0; m0 < MD; m0 += mc) {
        int mrows = (MD - m0 < mc) ? (MD - m0) : mc;   // multiple of 256
        int n8 = mrows * (KD / 8);
        cvt_kernel<<<(n8 + 255) / 256, 256, 0, stream>>>(x + (size_t)m0 * KD, xbuf, n8);
        for (int n0 = 0; n0 < ND; n0 += nc) {
            int nrows = (ND - n0 < nc) ? (ND - n0) : nc;  // multiple of 256
            int tt = nrows * (KD / 8);
            dequant_kernel<<<(tt + 255) / 256, 256, 0, stream>>>(wp, sc, wbuf, n0, nrows);
            int mt = mrows / 256, nt2 = nrows / 256;
            gemm256<<<mt * nt2, 512, 0, stream>>>(xbuf, wbuf, out + (size_t)m0 * ND, mt, nt2, n0);
        }
    }
}

// Round 5
// 1413.821 us; speedup vs baseline: 1.9059x; 1.0345x over previous
//
#include <hip/hip_runtime.h>
#include <hip/hip_bf16.h>

#define KD 4096
#define ND 11008
#define MD 16384
#define KGD 32
#define NT (KD / 64)

typedef __hip_bfloat16 bf16;
typedef float f32x4 __attribute__((ext_vector_type(4)));
typedef short bf16x8 __attribute__((ext_vector_type(8)));

#define WAITV(n) asm volatile("s_waitcnt vmcnt(" #n ")" ::: "memory")

__device__ __forceinline__ void gload16(const bf16* g, bf16* l) {
    __builtin_amdgcn_global_load_lds((const __attribute__((address_space(1))) void*)g,
                                     (__attribute__((address_space(3))) void*)l, 16, 0, 0);
}

// ---------------------------------------------------------------------------
// x: fp32 -> bf16 (8 elems/thread)
// ---------------------------------------------------------------------------
__global__ void cvt_kernel(const float* __restrict__ x, bf16* __restrict__ y, int n8) {
    int i = blockIdx.x * blockDim.x + threadIdx.x;
    if (i >= n8) return;
    const f32x4* p = reinterpret_cast<const f32x4*>(x + (size_t)i * 8);
    f32x4 a = p[0], b = p[1];
    bf16 o[8];
#pragma unroll
    for (int e = 0; e < 4; ++e) {
        o[e]     = __float2bfloat16(a[e]);
        o[4 + e] = __float2bfloat16(b[e]);
    }
    *reinterpret_cast<bf16x8*>(y + (size_t)i * 8) = *reinterpret_cast<bf16x8*>(o);
}

// ---------------------------------------------------------------------------
// dequant packed int4 -> bf16 rows [n0 .. n0+rows) into wd (chunk-local)
// ---------------------------------------------------------------------------
__global__ void dequant_kernel(const int* __restrict__ wp, const float* __restrict__ sc,
                               bf16* __restrict__ wd, int n0, int rows) {
    const int per_row = KD / 8;
    int t = blockIdx.x * blockDim.x + threadIdx.x;
    if (t >= rows * per_row) return;
    int lr = t / per_row;
    int q  = t - lr * per_row;
    int n  = n0 + lr;
    int j  = q * 4;
    const int4 p = *reinterpret_cast<const int4*>(wp + (size_t)n * (KD / 2) + j);
    float s = sc[(size_t)n * KGD + (j >> 6)];
    int v[4] = {p.x, p.y, p.z, p.w};
    bf16 o[8];
#pragma unroll
    for (int i = 0; i < 4; ++i) {
        o[2 * i]     = __float2bfloat16((float)((v[i] & 0xF) - 8) * s);
        o[2 * i + 1] = __float2bfloat16((float)(((v[i] >> 4) & 0xF) - 8) * s);
    }
    *reinterpret_cast<bf16x8*>(wd + (size_t)lr * KD + j * 2) = *reinterpret_cast<bf16x8*>(o);
}

// ---------------------------------------------------------------------------
// GEMM: C[M,N] = A[M,K] * B[N,K]^T, all bf16 in, fp32 out.
// 256x256 tile, BK=64 (two K=32 units), 512 thr / 8 waves (2M x 4N),
// per-wave out 128x64. Double-buffered 128 KiB LDS, global_load_lds with
// pre-swizzled source (conflict-free ds_read_b128, verified 0 conflicts),
// counted vmcnt(8), ONE raw s_barrier per K-tile: both halves' 24 ds_reads +
// 64 MFMA live in a single scheduling window so LDS reads overlap MFMA.
// ---------------------------------------------------------------------------
__global__ __launch_bounds__(512, 2) void gemm256(const bf16* __restrict__ A,
                                                  const bf16* __restrict__ B,
                                                  float* __restrict__ C,
                                                  int mtiles, int ntiles, int n0base) {
    __shared__ bf16 lds[2][2][2][8192];  // [buf][kh][op(A/B)][256 rows x 32 k, swizzled]
    const int tid  = threadIdx.x;
    const int lane = tid & 63;
    const int w    = tid >> 6;

    // bijective XCD-aware block swizzle (n fastest: consecutive share A-panel)
    int nwg = mtiles * ntiles;
    int orig = blockIdx.x;
    int q8 = nwg >> 3, r8 = nwg & 7;
    int xcd = orig & 7, off = orig >> 3;
    int wg = (xcd < r8 ? xcd * (q8 + 1) : r8 * (q8 + 1) + (xcd - r8) * q8) + off;
    const int mb = wg / ntiles, nb = wg - mb * ntiles;
    const int m0 = mb * 256, n0 = nb * 256;

    const int wm = w >> 2, wn = w & 3;
    const int rl = lane & 15, kq = lane >> 4;
    const int sz = (rl >> 1) & 3;
    const int ro = 8 * (kq ^ sz);          // swizzled k-chunk for ds_read

    // staging source (per-lane pre-swizzle so linear LDS dest == swizzled layout)
    const int src_c = (((lane & 3) ^ ((lane >> 3) & 3)) << 3);  // elem offset in k
    const int src_r = (w << 4) + (lane >> 2);                   // row (+128 for issue 1)
    const bf16* Abase = A + (size_t)(m0 + src_r) * KD + src_c;
    const bf16* Bbase = B + (size_t)(n0 + src_r) * KD + src_c;

    f32x4 acc[8][4] = {};

    auto stage = [&](int buf, int kh, int k0) {
        const bf16* ga = Abase + k0 + kh * 32;
        const bf16* gb = Bbase + k0 + kh * 32;
        bf16* la = &lds[buf][kh][0][w * 512];
        bf16* lb = &lds[buf][kh][1][w * 512];
        gload16(ga, la);
        gload16(ga + (size_t)128 * KD, la + 4096);
        gload16(gb, lb);
        gload16(gb + (size_t)128 * KD, lb + 4096);
    };

    auto compute = [&](int buf, int kh) {
        const bf16* ua = &lds[buf][kh][0][0];
        const bf16* ub = &lds[buf][kh][1][0];
        bf16x8 af[8], bfr[4];
#pragma unroll
        for (int mi = 0; mi < 8; ++mi)
            af[mi] = *reinterpret_cast<const bf16x8*>(&ua[(wm * 128 + mi * 16 + rl) * 32 + ro]);
#pragma unroll
        for (int ni = 0; ni < 4; ++ni)
            bfr[ni] = *reinterpret_cast<const bf16x8*>(&ub[(wn * 64 + ni * 16 + rl) * 32 + ro]);
        __builtin_amdgcn_s_setprio(1);
#pragma unroll
        for (int mi = 0; mi < 8; ++mi)
#pragma unroll
            for (int ni = 0; ni < 4; ++ni)
                acc[mi][ni] = __builtin_amdgcn_mfma_f32_16x16x32_bf16(
                    af[mi], bfr[ni], acc[mi][ni], 0, 0, 0);
        __builtin_amdgcn_s_setprio(0);
    };

    // prologue: tile 0 -> buf 0 (8 loads outstanding)
    stage(0, 0, 0);
    stage(0, 1, 0);

    for (int t = 0; t < NT - 1; ++t) {
        const int cur = t & 1, nxt = cur ^ 1, k0n = (t + 1) * 64;
        stage(nxt, 0, k0n);     // +8 -> 16 outstanding
        stage(nxt, 1, k0n);
        WAITV(8);               // tile t fully landed (newest 8 = tile t+1)
        __builtin_amdgcn_s_barrier();
        compute(cur, 0);        // one scheduling window: 24 ds_read + 64 MFMA
        compute(cur, 1);
    }
    // tail: tile NT-1 (odd -> buf 1); drain fully
    WAITV(0);
    __builtin_amdgcn_s_barrier();
    compute(1, 0);
    compute(1, 1);

    // epilogue: C/D layout col=lane&15, row=(lane>>4)*4+r ; fp32 out
    const int crow = m0 + wm * 128 + kq * 4;
    const int ccol = n0base + n0 + wn * 64 + rl;
#pragma unroll
    for (int mi = 0; mi < 8; ++mi) {
#pragma unroll
        for (int r = 0; r < 4; ++r) {
            float* cp = C + (size_t)(crow + mi * 16 + r) * ND + ccol;
#pragma unroll
            for (int ni = 0; ni < 4; ++ni)
                cp[ni * 16] = acc[mi][ni][r];
        }
    }
}

extern "C" void kernel_launch(void* const* d_in, const int* in_sizes, int n_in,
                              void* d_out, int out_size, void* d_ws, size_t ws_size,
                              hipStream_t stream) {
    const float* x  = (const float*)d_in[0];
    const int*   wp = (const int*)d_in[1];
    const float* sc = (const float*)d_in[2];
    float* out = (float*)d_out;

    // partition ws into x-bf16 chunk (mc rows) + W-bf16 chunk (nc rows), both x256
    long long rows_cap = (long long)(ws_size / ((size_t)KD * 2));
    int mc, nc;
    if (rows_cap >= MD + 256) {
        mc = MD;
        long long r = rows_cap - MD;
        nc = (int)((r / 256) * 256);
        if (nc > ND) nc = ND;
    } else if (rows_cap >= ND + 256) {
        nc = ND;
        long long r = rows_cap - ND;
        mc = (int)((r / 256) * 256);
        if (mc > MD) mc = MD;
    } else {
        nc = (int)(((rows_cap / 2) / 256) * 256);
        if (nc > ND) nc = ND;
        long long r = rows_cap - nc;
        mc = (int)((r / 256) * 256);
        if (mc > MD) mc = MD;
        if (mc <= 0 || nc <= 0) return;
    }

    bf16* xbuf = (bf16*)d_ws;
    bf16* wbuf = xbuf + (size_t)mc * KD;

    for (int m0 = 0; m0 < MD; m0 += mc) {
        int mrows = (MD - m0 < mc) ? (MD - m0) : mc;   // multiple of 256
        int n8 = mrows * (KD / 8);
        cvt_kernel<<<(n8 + 255) / 256, 256, 0, stream>>>(x + (size_t)m0 * KD, xbuf, n8);
        for (int n0 = 0; n0 < ND; n0 += nc) {
            int nrows = (ND - n0 < nc) ? (ND - n0) : nc;  // multiple of 256
            int tt = nrows * (KD / 8);
            dequant_kernel<<<(tt + 255) / 256, 256, 0, stream>>>(wp, sc, wbuf, n0, nrows);
            int mt = mrows / 256, nt2 = nrows / 256;
            gemm256<<<mt * nt2, 512, 0, stream>>>(xbuf, wbuf, out + (size_t)m0 * ND, mt, nt2, n0);
        }
    }
}